// Round 3
// 486.457 us; speedup vs baseline: 1.0475x; 1.0475x over previous
//
#include <hip/hip_runtime.h>
#include <math.h>

namespace {
constexpr int Ln   = 2048;
constexpr int Kn   = 32;
constexpr int EFn  = 128;
constexpr int ROWS = 4 * Ln;                               // 8192
constexpr size_t V_ELEMS = (size_t)ROWS * EFn;             // 1048576
constexpr size_t E_ELEMS = (size_t)ROWS * Kn * EFn;        // 33554432
constexpr size_t IDX_OFF = V_ELEMS + E_ELEMS;              // 34603008

typedef float f32x4 __attribute__((ext_vector_type(4)));   // nontemporal-builtin-compatible

__device__ __forceinline__ unsigned int orderKey(float f) {
  unsigned int u = __float_as_uint(f);
  return (u & 0x80000000u) ? ~u : (u | 0x80000000u);
}
__device__ __forceinline__ float keyToFloat(unsigned int k) {
  unsigned int u = (k & 0x80000000u) ? (k & 0x7fffffffu) : ~k;
  return __uint_as_float(u);
}
__device__ __forceinline__ unsigned long long u64min(unsigned long long a, unsigned long long b) {
  return a < b ? a : b;
}
// float4-chunk swizzle within a 128-float row: chunk q -> (q&~3)|((q+(q>>2))&3)
// reader (sub,w): position (sub<<2)|((w+sub)&3). Max 2-way bank aliasing (free, m136).
__device__ __forceinline__ int swzChunk(int q) {
  return (q & ~3) | ((q + (q >> 2)) & 3);
}
} // namespace

// T[n][d][c] = sum_m (pos_W[d,m] + pos_b[m]) * edge_W[n*16+m, c]   (7*66*128 f32 = 236,544 B)
__global__ void pf_tab(const float* __restrict__ pos_W, const float* __restrict__ pos_b,
                       const float* __restrict__ edge_W, float* __restrict__ T) {
  int n = blockIdx.x / 66, dd = blockIdx.x % 66, c = threadIdx.x;
  float acc = 0.f;
#pragma unroll
  for (int m = 0; m < 16; m++)
    acc += (pos_W[dd * 16 + m] + pos_b[m]) * edge_W[(n * 16 + m) * EFn + c];
  T[(size_t)(n * 66 + dd) * EFn + c] = acc;
}

__global__ __launch_bounds__(256) void pf_main(
    const float* __restrict__ dist_ca, const float* __restrict__ omega,
    const float* __restrict__ theta, const float* __restrict__ phi,
    const float* __restrict__ dihedral, const float* __restrict__ mask_angle,
    const int* __restrict__ Sarr, const int* __restrict__ ridx,
    const int* __restrict__ chain, const float* __restrict__ T,
    const float* __restrict__ edge_W, const float* __restrict__ ln_e_g,
    const float* __restrict__ ln_e_b, const float* __restrict__ embed_tab,
    const float* __restrict__ node_W, const float* __restrict__ node_b,
    const float* __restrict__ ln_n_g, const float* __restrict__ ln_n_b,
    float* __restrict__ out) {
  __shared__ __align__(16) float s_W2[16 * EFn];           // 8 KB, swizzled RBF weight rows
  __shared__ __align__(16) float s_lng[EFn], s_lnb[EFn];   // 1 KB, swizzled LN params
  __shared__ __align__(16) unsigned int s_hist[256];
  __shared__ unsigned long long s_cand[64];
  __shared__ unsigned long long s_w64[4];
  __shared__ float s_mx[4], s_mn2[4], s_mx2[4];
  __shared__ float s_v4[4];
  __shared__ int s_nidx[Kn];
  __shared__ float s_nval[Kn];
  __shared__ int s_d7[Kn * 8];
  __shared__ int s_bsel, s_tot, s_cnt;

  const int tid = threadIdx.x;
  const int lane = tid & 63, wid = tid >> 6;
  const int r = blockIdx.x;                    // row = b*L + i
  const int b = r >> 11;
  const size_t rowoff = (size_t)r * Ln;

  // ---------- Stage W2 (edge_W rows 112..127) + LN params into LDS (swizzled) ----------
#pragma unroll
  for (int it = 0; it < 2; it++) {
    int idx = tid + (it << 8);                 // 0..511
    int rr = idx >> 5, q = idx & 31;
    ((f32x4*)s_W2)[(rr << 5) + swzChunk(q)] =
        ((const f32x4*)(edge_W + (size_t)(112 + rr) * EFn))[q];
  }
  if (tid < 64) {
    int q = tid & 31;
    const f32x4* src = (const f32x4*)((tid < 32) ? ln_e_g : ln_e_b);
    f32x4* dst = (f32x4*)((tid < 32) ? s_lng : s_lnb);
    dst[swzChunk(q)] = src[q];
  }
  s_hist[tid] = 0u;
  if (!tid) s_cnt = 0;

  // ---------- Phase 1: load row (f32x4 nontemporal), D = mask*dist, row max ----------
  float Dv[8], Mv[8];
  {
    const f32x4* dp = (const f32x4*)(dist_ca + rowoff) + (tid << 1);
    const f32x4* mp = (const f32x4*)(mask_angle + rowoff) + (tid << 1);
    f32x4 d0 = __builtin_nontemporal_load(dp);
    f32x4 d1 = __builtin_nontemporal_load(dp + 1);
    f32x4 m0v = __builtin_nontemporal_load(mp);
    f32x4 m1v = __builtin_nontemporal_load(mp + 1);
#pragma unroll
    for (int q = 0; q < 4; q++) { Mv[q] = m0v[q]; Mv[4 + q] = m1v[q]; }
#pragma unroll
    for (int q = 0; q < 4; q++) { Dv[q] = m0v[q] * d0[q]; Dv[4 + q] = m1v[q] * d1[q]; }
  }
  float lmax = -3.4e38f;
#pragma unroll
  for (int m = 0; m < 8; m++) lmax = fmaxf(lmax, Dv[m]);
#pragma unroll
  for (int o = 32; o; o >>= 1) lmax = fmaxf(lmax, __shfl_xor(lmax, o));
  if (!lane) s_mx[wid] = lmax;
  __syncthreads();                                               // B1
  const float Dmax = fmaxf(fmaxf(s_mx[0], s_mx[1]), fmaxf(s_mx[2], s_mx[3]));

  // ---------- Phase 2: adjust, min/max for bucketing ----------
  float lmin = 3.4e38f; lmax = -3.4e38f;
#pragma unroll
  for (int m = 0; m < 8; m++) {
    float adj = fmaf(1.0f - Mv[m], Dmax, Dv[m]);
    Dv[m] = adj;
    lmin = fminf(lmin, adj); lmax = fmaxf(lmax, adj);
  }
#pragma unroll
  for (int o = 32; o; o >>= 1) {
    lmin = fminf(lmin, __shfl_xor(lmin, o));
    lmax = fmaxf(lmax, __shfl_xor(lmax, o));
  }
  if (!lane) { s_mn2[wid] = lmin; s_mx2[wid] = lmax; }
  __syncthreads();                                               // B2
  const float m0 = fminf(fminf(s_mn2[0], s_mn2[1]), fminf(s_mn2[2], s_mn2[3]));
  const float M0 = fmaxf(fmaxf(s_mx2[0], s_mx2[1]), fmaxf(s_mx2[2], s_mx2[3]));
  const float rng = M0 - m0;
  const float scale = (rng > 0.f) ? 255.0f / rng : 0.f;

  // ---------- Phase 3: bucket histogram ----------
  int binv[8];
#pragma unroll
  for (int m = 0; m < 8; m++) {
    int bin = (int)((Dv[m] - m0) * scale);
    bin = bin < 0 ? 0 : (bin > 255 ? 255 : bin);
    binv[m] = bin;
    atomicAdd(&s_hist[bin], 1u);
  }
  __syncthreads();                                               // B3

  // ---------- Phase 4a: single-wave shuffle scan + bucket select (no barrier loop) ----------
  if (wid == 0) {
    uint4 h = ((const uint4*)s_hist)[lane];                      // bins 4l..4l+3
    unsigned c1 = h.x + h.y, c2 = c1 + h.z, c3 = c2 + h.w;
    unsigned pre = c3;
#pragma unroll
    for (int o = 1; o < 64; o <<= 1) {
      unsigned u = __shfl_up(pre, o);
      if (lane >= o) pre += u;
    }
    unsigned excl = pre - c3;
    unsigned cums[4]  = {excl + h.x, excl + c1, excl + c2, excl + c3};
    unsigned prevs[4] = {excl, excl + h.x, excl + c1, excl + c2};
#pragma unroll
    for (int q = 0; q < 4; q++)
      if (cums[q] >= (unsigned)Kn && prevs[q] < (unsigned)Kn) {
        s_bsel = (lane << 2) + q; s_tot = (int)cums[q];
      }
  }
  __syncthreads();                                               // B4
  const int bsel = s_bsel;
  const int tot = s_tot;

  // ---------- Phase 4b: collect candidates (fast path) ----------
  if (tot <= 64) {
#pragma unroll
    for (int m = 0; m < 8; m++) {
      if (binv[m] <= bsel) {
        int p = atomicAdd(&s_cnt, 1);
        s_cand[p] = ((unsigned long long)orderKey(Dv[m]) << 16) | (unsigned)((tid << 3) + m);
      }
    }
  }
  __syncthreads();                                               // B5

  if (tot <= 64) {
    // 64-lane bitonic sort ascending on (key,idx) — matches jax top_k tie-break
    if (tid < 64) {
      unsigned long long v = (tid < tot) ? s_cand[tid] : ~0ull;
#pragma unroll
      for (int size = 2; size <= 64; size <<= 1) {
        for (int stride = size >> 1; stride > 0; stride >>= 1) {
          unsigned long long p = __shfl_xor(v, stride);
          bool keepMin = (((tid & stride) == 0) == ((tid & size) == 0));
          v = ((v < p) != keepMin) ? p : v;
        }
      }
      if (tid < Kn) {
        s_nidx[tid] = (int)(v & 0xffffull);
        s_nval[tid] = keyToFloat((unsigned int)(v >> 16));
      }
    }
  } else {
    // exact fallback (rare: degenerate rows): 32x block-wide argmin on register keys
    for (int t = 0; t < Kn; t++) {
      unsigned long long lm = ~0ull;
#pragma unroll
      for (int m = 0; m < 8; m++) {
        unsigned long long kk =
            ((unsigned long long)orderKey(Dv[m]) << 16) | (unsigned)((tid << 3) + m);
        lm = u64min(lm, kk);
      }
#pragma unroll
      for (int o = 32; o; o >>= 1) lm = u64min(lm, __shfl_xor(lm, o));
      if (!lane) s_w64[wid] = lm;
      __syncthreads();
      unsigned long long g = u64min(u64min(s_w64[0], s_w64[1]), u64min(s_w64[2], s_w64[3]));
      int j = (int)(g & 0xffffull);
      {
        // statically-unrolled invalidation (avoid dynamic reg-array index -> scratch)
        bool own = ((j >> 3) == tid);
        int jm = j & 7;
#pragma unroll
        for (int m = 0; m < 8; m++)
          if (own && jm == m) Dv[m] = 3.4e38f;
      }
      if (!tid) { s_nidx[t] = j; s_nval[t] = keyToFloat((unsigned int)(g >> 16)); }
      __syncthreads();
    }
  }
  __syncthreads();                                               // B6

  // ---------- E_idx output + Phase 5: per-edge table indices d[0..6], 128 threads ----------
  const int ri_i = ridx[r];
  const int ch_i = chain[r];
  if (tid < Kn)
    out[IDX_OFF + (size_t)r * Kn + tid] = (float)s_nidx[tid];
  if (tid < 128) {
    const int k = tid & 31;
    const int grp = tid >> 5;                  // 0: offset, 1: omega, 2: theta, 3: phi
    const int j = s_nidx[k];
    const int sc = (ch_i == chain[(size_t)b * Ln + j]) ? 1 : 0;
    if (grp == 0) {
      int rj = ridx[(size_t)b * Ln + j];
      int d0 = ri_i - rj + 32;                 // trunc toward zero like .astype(int32)
      d0 = d0 < 0 ? 0 : (d0 > 64 ? 64 : d0);
      s_d7[(k << 3) + 0] = sc ? d0 : 65;
    } else {
      const float* src = (grp == 1) ? omega : (grp == 2) ? theta : phi;
      float v = src[rowoff + j];
      float cva = cosf(v), sva = sinf(v);
      int dc = (int)cva + 32; dc = dc < 0 ? 0 : (dc > 64 ? 64 : dc);
      int ds_ = (int)sva + 32; ds_ = ds_ < 0 ? 0 : (ds_ > 64 ? 64 : ds_);
      s_d7[(k << 3) + (grp << 1) - 1] = sc ? dc : 65;
      s_d7[(k << 3) + (grp << 1)]     = sc ? ds_ : 65;
    }
  }
  __syncthreads();                                               // B7

  // ---------- Phase 7a: node features partial (overlaps with Phase 6) ----------
  float a = 0.f;
  if (tid < EFn) {
    const int c = tid;
    const int sv2 = Sarr[r];
    a = node_b[c];
#pragma unroll
    for (int m = 0; m < 6; m++) a = fmaf(embed_tab[sv2 * 6 + m], node_W[m * EFn + c], a);
#pragma unroll
    for (int m = 0; m < 6; m++) a = fmaf(dihedral[(size_t)r * 6 + m], node_W[(6 + m) * EFn + c], a);
    float s1 = a, s2 = a * a;
#pragma unroll
    for (int o = 32; o; o >>= 1) { s1 += __shfl_xor(s1, o); s2 += __shfl_xor(s2, o); }
    if (!lane) { s_v4[wid * 2] = s1; s_v4[wid * 2 + 1] = s2; }
  }

  // ---------- Phase 6: edge features: 32 edges x 8 threads x 16 channels ----------
  {
    const int k = tid >> 3, sub = tid & 7, c0 = sub << 4;
    float acc[16];
    {
      const f32x4* Tp = (const f32x4*)(T + (size_t)s_d7[k << 3] * EFn + c0);
      f32x4 a0 = Tp[0], a1 = Tp[1], a2 = Tp[2], a3 = Tp[3];
#pragma unroll
      for (int q = 0; q < 4; q++) {
        acc[q] = a0[q]; acc[4 + q] = a1[q]; acc[8 + q] = a2[q]; acc[12 + q] = a3[q];
      }
    }
#pragma unroll
    for (int n = 1; n < 7; n++) {
      const f32x4* Tp = (const f32x4*)(T + (size_t)(n * 66 + s_d7[(k << 3) + n]) * EFn + c0);
      f32x4 a0 = Tp[0], a1 = Tp[1], a2 = Tp[2], a3 = Tp[3];
#pragma unroll
      for (int q = 0; q < 4; q++) {
        acc[q] += a0[q]; acc[4 + q] += a1[q]; acc[8 + q] += a2[q]; acc[12 + q] += a3[q];
      }
    }
    const float dv = s_nval[k];
#pragma unroll
    for (int rr = 0; rr < 16; rr++) {
      float mu = 2.0f + (20.0f / 15.0f) * (float)rr;
      float t = (dv - mu) * 0.8f;               // 1/1.25
      float rb = expf(-t * t);
      const f32x4* Wr = (const f32x4*)(s_W2 + (rr << 7));
#pragma unroll
      for (int w = 0; w < 4; w++) {
        f32x4 wv = Wr[(sub << 2) | ((w + sub) & 3)];   // de-swizzled read, <=2-way banks
#pragma unroll
        for (int q = 0; q < 4; q++)
          acc[(w << 2) + q] = fmaf(rb, wv[q], acc[(w << 2) + q]);
      }
    }
    // LayerNorm over 128 channels = 8 consecutive lanes
    float s1 = 0.f, s2 = 0.f;
#pragma unroll
    for (int m = 0; m < 16; m++) { s1 += acc[m]; s2 += acc[m] * acc[m]; }
#pragma unroll
    for (int o = 1; o < 8; o <<= 1) { s1 += __shfl_xor(s1, o); s2 += __shfl_xor(s2, o); }
    const float mean = s1 * (1.0f / 128.0f);
    float var = s2 * (1.0f / 128.0f) - mean * mean;
    var = fmaxf(var, 0.f);
    const float inv = rsqrtf(var + 1e-5f);
    f32x4* dst = (f32x4*)(out + V_ELEMS + ((size_t)(r * Kn + k) * EFn + c0));
#pragma unroll
    for (int w = 0; w < 4; w++) {
      int p = (sub << 2) | ((w + sub) & 3);
      f32x4 g = ((const f32x4*)s_lng)[p];
      f32x4 bb = ((const f32x4*)s_lnb)[p];
      f32x4 o4;
#pragma unroll
      for (int q = 0; q < 4; q++)
        o4[q] = (acc[(w << 2) + q] - mean) * inv * g[q] + bb[q];
      __builtin_nontemporal_store(o4, dst + w);
    }
  }
  __syncthreads();                                               // B8

  // ---------- Phase 7b: finalize node features V ----------
  if (tid < EFn) {
    const float S1 = s_v4[0] + s_v4[2], S2 = s_v4[1] + s_v4[3];
    const float mean = S1 * (1.0f / 128.0f);
    float var = S2 * (1.0f / 128.0f) - mean * mean;
    var = fmaxf(var, 0.f);
    const float inv = rsqrtf(var + 1e-5f);
    out[(size_t)r * EFn + tid] = (a - mean) * inv * ln_n_g[tid] + ln_n_b[tid];
  }
}

extern "C" void kernel_launch(void* const* d_in, const int* in_sizes, int n_in,
                              void* d_out, int out_size, void* d_ws, size_t ws_size,
                              hipStream_t stream) {
  (void)in_sizes; (void)n_in; (void)out_size; (void)ws_size;
  const float* dist_ca    = (const float*)d_in[0];
  const float* omega      = (const float*)d_in[1];
  const float* theta      = (const float*)d_in[2];
  const float* phi        = (const float*)d_in[3];
  const float* dihedral   = (const float*)d_in[4];
  const float* mask_angle = (const float*)d_in[5];
  // d_in[6] = mask (unused by reference)
  const int*   S          = (const int*)d_in[7];
  const int*   ridx       = (const int*)d_in[8];
  const int*   chain      = (const int*)d_in[9];
  const float* pos_W      = (const float*)d_in[10];
  const float* pos_b      = (const float*)d_in[11];
  const float* edge_W     = (const float*)d_in[12];
  const float* ln_e_g     = (const float*)d_in[13];
  const float* ln_e_b     = (const float*)d_in[14];
  const float* embed_tab  = (const float*)d_in[15];
  const float* node_W     = (const float*)d_in[16];
  const float* node_b     = (const float*)d_in[17];
  const float* ln_n_g     = (const float*)d_in[18];
  const float* ln_n_b     = (const float*)d_in[19];

  float* T = (float*)d_ws;   // 7*66*128*4 = 236,544 bytes

  pf_tab<<<7 * 66, 128, 0, stream>>>(pos_W, pos_b, edge_W, T);
  pf_main<<<ROWS, 256, 0, stream>>>(dist_ca, omega, theta, phi, dihedral, mask_angle,
                                    S, ridx, chain, T, edge_W, ln_e_g, ln_e_b,
                                    embed_tab, node_W, node_b, ln_n_g, ln_n_b,
                                    (float*)d_out);
}

// Round 4
// 420.283 us; speedup vs baseline: 1.2124x; 1.1574x over previous
//
#include <hip/hip_runtime.h>
#include <math.h>

namespace {
constexpr int Ln   = 2048;
constexpr int Kn   = 32;
constexpr int EFn  = 128;
constexpr int ROWS = 4 * Ln;                               // 8192
constexpr size_t V_ELEMS = (size_t)ROWS * EFn;             // 1048576
constexpr size_t E_ELEMS = (size_t)ROWS * Kn * EFn;        // 33554432
constexpr size_t IDX_OFF = V_ELEMS + E_ELEMS;              // 34603008

typedef float f32x4 __attribute__((ext_vector_type(4)));   // nontemporal-builtin-compatible

__device__ __forceinline__ unsigned int orderKey(float f) {
  unsigned int u = __float_as_uint(f);
  return (u & 0x80000000u) ? ~u : (u | 0x80000000u);
}
__device__ __forceinline__ float keyToFloat(unsigned int k) {
  unsigned int u = (k & 0x80000000u) ? (k & 0x7fffffffu) : ~k;
  return __uint_as_float(u);
}
__device__ __forceinline__ unsigned long long u64min(unsigned long long a, unsigned long long b) {
  return a < b ? a : b;
}
// Chunk permutation within a 128-float row (32 float4 chunks viewed as 8x4, transposed):
//   perm(q) = ((q&3)<<3) | (q>>2)
// Reader (sub,w) wants chunk q = 4*sub+w  ->  reads position (w<<3)|sub.
// At fixed w the 8 distinct float4 addrs have (pos mod 8) = sub -> 8 distinct 4-bank
// groups -> conflict-free ds_read_b128. Writer (q=0..31 per 32 lanes) covers all 32
// banks evenly (4 words/bank minimum).
__device__ __forceinline__ int swzT(int q) {
  return ((q & 3) << 3) | (q >> 2);
}
} // namespace

// T[n][d][c] = sum_m (pos_W[d,m] + pos_b[m]) * edge_W[n*16+m, c]   (7*66*128 f32 = 236,544 B)
__global__ void pf_tab(const float* __restrict__ pos_W, const float* __restrict__ pos_b,
                       const float* __restrict__ edge_W, float* __restrict__ T) {
  int n = blockIdx.x / 66, dd = blockIdx.x % 66, c = threadIdx.x;
  float acc = 0.f;
#pragma unroll
  for (int m = 0; m < 16; m++)
    acc += (pos_W[dd * 16 + m] + pos_b[m]) * edge_W[(n * 16 + m) * EFn + c];
  T[(size_t)(n * 66 + dd) * EFn + c] = acc;
}

__global__ __launch_bounds__(256) void pf_main(
    const float* __restrict__ dist_ca, const float* __restrict__ omega,
    const float* __restrict__ theta, const float* __restrict__ phi,
    const float* __restrict__ dihedral, const float* __restrict__ mask_angle,
    const int* __restrict__ Sarr, const int* __restrict__ ridx,
    const int* __restrict__ chain, const float* __restrict__ T,
    const float* __restrict__ edge_W, const float* __restrict__ ln_e_g,
    const float* __restrict__ ln_e_b, const float* __restrict__ embed_tab,
    const float* __restrict__ node_W, const float* __restrict__ node_b,
    const float* __restrict__ ln_n_g, const float* __restrict__ ln_n_b,
    float* __restrict__ out) {
  __shared__ __align__(16) float s_W2[16 * EFn];           // 8 KB, swizzled RBF weight rows
  __shared__ __align__(16) float s_lng[EFn], s_lnb[EFn];   // 1 KB, swizzled LN params
  __shared__ __align__(16) unsigned int s_hist[256];
  __shared__ unsigned long long s_cand[64];
  __shared__ unsigned long long s_w64[4];
  __shared__ float s_mx[4], s_mn2[4], s_mx2[4];
  __shared__ float s_v4[4];
  __shared__ int s_nidx[Kn];
  __shared__ float s_nval[Kn];
  __shared__ int s_d7[Kn * 8];
  __shared__ int s_bsel, s_tot, s_cnt;

  const int tid = threadIdx.x;
  const int lane = tid & 63, wid = tid >> 6;
  const int r = blockIdx.x;                    // row = b*L + i
  const int b = r >> 11;
  const size_t rowoff = (size_t)r * Ln;

  // ---------- Stage W2 (edge_W rows 112..127) + LN params into LDS (swizzled) ----------
#pragma unroll
  for (int it = 0; it < 2; it++) {
    int idx = tid + (it << 8);                 // 0..511
    int rr = idx >> 5, q = idx & 31;
    ((f32x4*)s_W2)[(rr << 5) + swzT(q)] =
        ((const f32x4*)(edge_W + (size_t)(112 + rr) * EFn))[q];
  }
  if (tid < 64) {
    int q = tid & 31;
    const f32x4* src = (const f32x4*)((tid < 32) ? ln_e_g : ln_e_b);
    f32x4* dst = (f32x4*)((tid < 32) ? s_lng : s_lnb);
    dst[swzT(q)] = src[q];
  }
  s_hist[tid] = 0u;
  if (!tid) s_cnt = 0;

  // ---------- Phase 1: load row (f32x4 nontemporal), D = mask*dist, row max ----------
  float Dv[8], Mv[8];
  {
    const f32x4* dp = (const f32x4*)(dist_ca + rowoff) + (tid << 1);
    const f32x4* mp = (const f32x4*)(mask_angle + rowoff) + (tid << 1);
    f32x4 d0 = __builtin_nontemporal_load(dp);
    f32x4 d1 = __builtin_nontemporal_load(dp + 1);
    f32x4 m0v = __builtin_nontemporal_load(mp);
    f32x4 m1v = __builtin_nontemporal_load(mp + 1);
#pragma unroll
    for (int q = 0; q < 4; q++) { Mv[q] = m0v[q]; Mv[4 + q] = m1v[q]; }
#pragma unroll
    for (int q = 0; q < 4; q++) { Dv[q] = m0v[q] * d0[q]; Dv[4 + q] = m1v[q] * d1[q]; }
  }
  float lmax = -3.4e38f;
#pragma unroll
  for (int m = 0; m < 8; m++) lmax = fmaxf(lmax, Dv[m]);
#pragma unroll
  for (int o = 32; o; o >>= 1) lmax = fmaxf(lmax, __shfl_xor(lmax, o));
  if (!lane) s_mx[wid] = lmax;
  __syncthreads();                                               // B1
  const float Dmax = fmaxf(fmaxf(s_mx[0], s_mx[1]), fmaxf(s_mx[2], s_mx[3]));

  // ---------- Phase 2: adjust, min/max for bucketing ----------
  float lmin = 3.4e38f; lmax = -3.4e38f;
#pragma unroll
  for (int m = 0; m < 8; m++) {
    float adj = fmaf(1.0f - Mv[m], Dmax, Dv[m]);
    Dv[m] = adj;
    lmin = fminf(lmin, adj); lmax = fmaxf(lmax, adj);
  }
#pragma unroll
  for (int o = 32; o; o >>= 1) {
    lmin = fminf(lmin, __shfl_xor(lmin, o));
    lmax = fmaxf(lmax, __shfl_xor(lmax, o));
  }
  if (!lane) { s_mn2[wid] = lmin; s_mx2[wid] = lmax; }
  __syncthreads();                                               // B2
  const float m0 = fminf(fminf(s_mn2[0], s_mn2[1]), fminf(s_mn2[2], s_mn2[3]));
  const float M0 = fmaxf(fmaxf(s_mx2[0], s_mx2[1]), fmaxf(s_mx2[2], s_mx2[3]));
  const float rng = M0 - m0;
  const float scale = (rng > 0.f) ? 255.0f / rng : 0.f;

  // ---------- Phase 3: bucket histogram ----------
  int binv[8];
#pragma unroll
  for (int m = 0; m < 8; m++) {
    int bin = (int)((Dv[m] - m0) * scale);
    bin = bin < 0 ? 0 : (bin > 255 ? 255 : bin);
    binv[m] = bin;
    atomicAdd(&s_hist[bin], 1u);
  }
  __syncthreads();                                               // B3

  // ---------- Phase 4a: single-wave shuffle scan + bucket select (no barrier loop) ----------
  if (wid == 0) {
    uint4 h = ((const uint4*)s_hist)[lane];                      // bins 4l..4l+3
    unsigned c1 = h.x + h.y, c2 = c1 + h.z, c3 = c2 + h.w;
    unsigned pre = c3;
#pragma unroll
    for (int o = 1; o < 64; o <<= 1) {
      unsigned u = __shfl_up(pre, o);
      if (lane >= o) pre += u;
    }
    unsigned excl = pre - c3;
    unsigned cums[4]  = {excl + h.x, excl + c1, excl + c2, excl + c3};
    unsigned prevs[4] = {excl, excl + h.x, excl + c1, excl + c2};
#pragma unroll
    for (int q = 0; q < 4; q++)
      if (cums[q] >= (unsigned)Kn && prevs[q] < (unsigned)Kn) {
        s_bsel = (lane << 2) + q; s_tot = (int)cums[q];
      }
  }
  __syncthreads();                                               // B4
  const int bsel = s_bsel;
  const int tot = s_tot;

  // ---------- Phase 4b: collect candidates (fast path) ----------
  if (tot <= 64) {
#pragma unroll
    for (int m = 0; m < 8; m++) {
      if (binv[m] <= bsel) {
        int p = atomicAdd(&s_cnt, 1);
        s_cand[p] = ((unsigned long long)orderKey(Dv[m]) << 16) | (unsigned)((tid << 3) + m);
      }
    }
  }
  __syncthreads();                                               // B5

  if (tot <= 64) {
    // 64-lane bitonic sort ascending on (key,idx) — matches jax top_k tie-break
    if (tid < 64) {
      unsigned long long v = (tid < tot) ? s_cand[tid] : ~0ull;
#pragma unroll
      for (int size = 2; size <= 64; size <<= 1) {
        for (int stride = size >> 1; stride > 0; stride >>= 1) {
          unsigned long long p = __shfl_xor(v, stride);
          bool keepMin = (((tid & stride) == 0) == ((tid & size) == 0));
          v = ((v < p) != keepMin) ? p : v;
        }
      }
      if (tid < Kn) {
        s_nidx[tid] = (int)(v & 0xffffull);
        s_nval[tid] = keyToFloat((unsigned int)(v >> 16));
      }
    }
  } else {
    // exact fallback (rare: degenerate rows): 32x block-wide argmin on register keys
    for (int t = 0; t < Kn; t++) {
      unsigned long long lm = ~0ull;
#pragma unroll
      for (int m = 0; m < 8; m++) {
        unsigned long long kk =
            ((unsigned long long)orderKey(Dv[m]) << 16) | (unsigned)((tid << 3) + m);
        lm = u64min(lm, kk);
      }
#pragma unroll
      for (int o = 32; o; o >>= 1) lm = u64min(lm, __shfl_xor(lm, o));
      if (!lane) s_w64[wid] = lm;
      __syncthreads();
      unsigned long long g = u64min(u64min(s_w64[0], s_w64[1]), u64min(s_w64[2], s_w64[3]));
      int j = (int)(g & 0xffffull);
      {
        // statically-unrolled invalidation (avoid dynamic reg-array index -> scratch)
        bool own = ((j >> 3) == tid);
        int jm = j & 7;
#pragma unroll
        for (int m = 0; m < 8; m++)
          if (own && jm == m) Dv[m] = 3.4e38f;
      }
      if (!tid) { s_nidx[t] = j; s_nval[t] = keyToFloat((unsigned int)(g >> 16)); }
      __syncthreads();
    }
  }
  __syncthreads();                                               // B6

  // ---------- E_idx output + Phase 5: per-edge table indices d[0..6], 128 threads ----------
  const int ri_i = ridx[r];
  const int ch_i = chain[r];
  if (tid < Kn)
    out[IDX_OFF + (size_t)r * Kn + tid] = (float)s_nidx[tid];
  if (tid < 128) {
    const int k = tid & 31;
    const int grp = tid >> 5;                  // 0: offset, 1: omega, 2: theta, 3: phi
    const int j = s_nidx[k];
    const int sc = (ch_i == chain[(size_t)b * Ln + j]) ? 1 : 0;
    if (grp == 0) {
      int rj = ridx[(size_t)b * Ln + j];
      int d0 = ri_i - rj + 32;                 // trunc toward zero like .astype(int32)
      d0 = d0 < 0 ? 0 : (d0 > 64 ? 64 : d0);
      s_d7[(k << 3) + 0] = sc ? d0 : 65;
    } else {
      const float* src = (grp == 1) ? omega : (grp == 2) ? theta : phi;
      float v = src[rowoff + j];
      float cva = cosf(v), sva = sinf(v);
      int dc = (int)cva + 32; dc = dc < 0 ? 0 : (dc > 64 ? 64 : dc);
      int ds_ = (int)sva + 32; ds_ = ds_ < 0 ? 0 : (ds_ > 64 ? 64 : ds_);
      s_d7[(k << 3) + (grp << 1) - 1] = sc ? dc : 65;
      s_d7[(k << 3) + (grp << 1)]     = sc ? ds_ : 65;
    }
  }
  __syncthreads();                                               // B7

  // ---------- Phase 7a: node features partial (overlaps with Phase 6) ----------
  float a = 0.f;
  if (tid < EFn) {
    const int c = tid;
    const int sv2 = Sarr[r];
    a = node_b[c];
#pragma unroll
    for (int m = 0; m < 6; m++) a = fmaf(embed_tab[sv2 * 6 + m], node_W[m * EFn + c], a);
#pragma unroll
    for (int m = 0; m < 6; m++) a = fmaf(dihedral[(size_t)r * 6 + m], node_W[(6 + m) * EFn + c], a);
    float s1 = a, s2 = a * a;
#pragma unroll
    for (int o = 32; o; o >>= 1) { s1 += __shfl_xor(s1, o); s2 += __shfl_xor(s2, o); }
    if (!lane) { s_v4[wid * 2] = s1; s_v4[wid * 2 + 1] = s2; }
  }

  // ---------- Phase 6: edge features: 32 edges x 8 threads x 16 channels ----------
  {
    const int k = tid >> 3, sub = tid & 7, c0 = sub << 4;
    float acc[16];
    {
      const f32x4* Tp = (const f32x4*)(T + (size_t)s_d7[k << 3] * EFn + c0);
      f32x4 a0 = Tp[0], a1 = Tp[1], a2 = Tp[2], a3 = Tp[3];
#pragma unroll
      for (int q = 0; q < 4; q++) {
        acc[q] = a0[q]; acc[4 + q] = a1[q]; acc[8 + q] = a2[q]; acc[12 + q] = a3[q];
      }
    }
#pragma unroll
    for (int n = 1; n < 7; n++) {
      const f32x4* Tp = (const f32x4*)(T + (size_t)(n * 66 + s_d7[(k << 3) + n]) * EFn + c0);
      f32x4 a0 = Tp[0], a1 = Tp[1], a2 = Tp[2], a3 = Tp[3];
#pragma unroll
      for (int q = 0; q < 4; q++) {
        acc[q] += a0[q]; acc[4 + q] += a1[q]; acc[8 + q] += a2[q]; acc[12 + q] += a3[q];
      }
    }
    const float dv = s_nval[k];
#pragma unroll
    for (int rr = 0; rr < 16; rr++) {
      float mu = 2.0f + (20.0f / 15.0f) * (float)rr;
      float t = (dv - mu) * 0.8f;               // 1/1.25
      float rb = __expf(-t * t);
      const f32x4* Wr = (const f32x4*)(s_W2 + (rr << 7));
#pragma unroll
      for (int w = 0; w < 4; w++) {
        f32x4 wv = Wr[(w << 3) | sub];          // conflict-free: bank-group = sub
#pragma unroll
        for (int q = 0; q < 4; q++)
          acc[(w << 2) + q] = fmaf(rb, wv[q], acc[(w << 2) + q]);
      }
    }
    // LayerNorm over 128 channels = 8 consecutive lanes
    float s1 = 0.f, s2 = 0.f;
#pragma unroll
    for (int m = 0; m < 16; m++) { s1 += acc[m]; s2 += acc[m] * acc[m]; }
#pragma unroll
    for (int o = 1; o < 8; o <<= 1) { s1 += __shfl_xor(s1, o); s2 += __shfl_xor(s2, o); }
    const float mean = s1 * (1.0f / 128.0f);
    float var = s2 * (1.0f / 128.0f) - mean * mean;
    var = fmaxf(var, 0.f);
    const float inv = rsqrtf(var + 1e-5f);
    f32x4* dst = (f32x4*)(out + V_ELEMS + ((size_t)(r * Kn + k) * EFn + c0));
#pragma unroll
    for (int w = 0; w < 4; w++) {
      int p = (w << 3) | sub;
      f32x4 g = ((const f32x4*)s_lng)[p];
      f32x4 bb = ((const f32x4*)s_lnb)[p];
      f32x4 o4;
#pragma unroll
      for (int q = 0; q < 4; q++)
        o4[q] = (acc[(w << 2) + q] - mean) * inv * g[q] + bb[q];
      dst[w] = o4;                              // plain store: L2 write-combining
    }
  }
  __syncthreads();                                               // B8

  // ---------- Phase 7b: finalize node features V ----------
  if (tid < EFn) {
    const float S1 = s_v4[0] + s_v4[2], S2 = s_v4[1] + s_v4[3];
    const float mean = S1 * (1.0f / 128.0f);
    float var = S2 * (1.0f / 128.0f) - mean * mean;
    var = fmaxf(var, 0.f);
    const float inv = rsqrtf(var + 1e-5f);
    out[(size_t)r * EFn + tid] = (a - mean) * inv * ln_n_g[tid] + ln_n_b[tid];
  }
}

extern "C" void kernel_launch(void* const* d_in, const int* in_sizes, int n_in,
                              void* d_out, int out_size, void* d_ws, size_t ws_size,
                              hipStream_t stream) {
  (void)in_sizes; (void)n_in; (void)out_size; (void)ws_size;
  const float* dist_ca    = (const float*)d_in[0];
  const float* omega      = (const float*)d_in[1];
  const float* theta      = (const float*)d_in[2];
  const float* phi        = (const float*)d_in[3];
  const float* dihedral   = (const float*)d_in[4];
  const float* mask_angle = (const float*)d_in[5];
  // d_in[6] = mask (unused by reference)
  const int*   S          = (const int*)d_in[7];
  const int*   ridx       = (const int*)d_in[8];
  const int*   chain      = (const int*)d_in[9];
  const float* pos_W      = (const float*)d_in[10];
  const float* pos_b      = (const float*)d_in[11];
  const float* edge_W     = (const float*)d_in[12];
  const float* ln_e_g     = (const float*)d_in[13];
  const float* ln_e_b     = (const float*)d_in[14];
  const float* embed_tab  = (const float*)d_in[15];
  const float* node_W     = (const float*)d_in[16];
  const float* node_b     = (const float*)d_in[17];
  const float* ln_n_g     = (const float*)d_in[18];
  const float* ln_n_b     = (const float*)d_in[19];

  float* T = (float*)d_ws;   // 7*66*128*4 = 236,544 bytes

  pf_tab<<<7 * 66, 128, 0, stream>>>(pos_W, pos_b, edge_W, T);
  pf_main<<<ROWS, 256, 0, stream>>>(dist_ca, omega, theta, phi, dihedral, mask_angle,
                                    S, ridx, chain, T, edge_W, ln_e_g, ln_e_b,
                                    embed_tab, node_W, node_b, ln_n_g, ln_n_b,
                                    (float*)d_out);
}